// Round 1
// baseline (53.468 us; speedup 1.0000x reference)
//
#include <hip/hip_runtime.h>

#define NN 512   // points per event (N == M)
#define DD 9     // num classes
#define LL 32    // latent dim

__global__ __launch_bounds__(512)
void loss_kernel(const float* __restrict__ kine_input,
                 const float* __restrict__ class_input,
                 const float* __restrict__ kine_pred,
                 const float* __restrict__ class_pred,
                 const float* __restrict__ mu,
                 const float* __restrict__ log_var,
                 float* __restrict__ out)
{
    const int b = blockIdx.x;
    const int t = threadIdx.x;   // 0..511

    __shared__ float4 sk_in[NN];   // kine_input rows (K=4)
    __shared__ float4 sk_pr[NN];   // kine_pred rows
    __shared__ float  red[8];      // per-wave partial sums
    __shared__ float  s_kl;
    __shared__ int    hist_in[DD];
    __shared__ int    hist_pr[DD];

    // ---- stage kine points in LDS (one float4 row per thread) ----
    sk_in[t] = *reinterpret_cast<const float4*>(kine_input + ((size_t)b * NN + t) * 4);
    sk_pr[t] = *reinterpret_cast<const float4*>(kine_pred  + ((size_t)b * NN + t) * 4);
    if (t < DD) { hist_in[t] = 0; hist_pr[t] = 0; }
    __syncthreads();

    // ---- pass 1: row t, min over all preds m ----
    float4 x = sk_in[t];
    float best1 = 1e30f; int bidx1 = 0;
    #pragma unroll 4
    for (int m = 0; m < NN; ++m) {
        float4 y = sk_pr[m];                       // LDS broadcast (all lanes same addr)
        float dx = x.x - y.x, dy = x.y - y.y;
        float dz = x.z - y.z, dw = x.w - y.w;
        float d = dx*dx + dy*dy + dz*dz + dw*dw;
        if (d < best1) { best1 = d; bidx1 = m; }   // strict < keeps first index (jnp.argmin)
    }

    // ---- pass 2: col t, min over all inputs n ----
    float4 yv = sk_pr[t];
    float best2 = 1e30f; int bidx2 = 0;
    #pragma unroll 4
    for (int n = 0; n < NN; ++n) {
        float4 xv = sk_in[n];
        float dx = xv.x - yv.x, dy = xv.y - yv.y;
        float dz = xv.z - yv.z, dw = xv.w - yv.w;
        float d = dx*dx + dy*dy + dz*dz + dw*dw;
        if (d < best2) { best2 = d; bidx2 = n; }
    }

    // ---- class terms: the same thread owns row t (idx1) and col t (idx2) ----
    const float* ci_base = class_input + (size_t)b * NN * DD;
    const float* cp_base = class_pred  + (size_t)b * NN * DD;

    float cls_dots = 0.f;
    {   // term 1: class_pred[idx1[t]] . class_input[t]; label of class_input row t
        float ci[DD];
        #pragma unroll
        for (int d = 0; d < DD; ++d) ci[d] = ci_base[t * DD + d];
        const float* g = cp_base + (size_t)bidx1 * DD;
        float dot = 0.f, mx = ci[0]; int lab = 0;
        #pragma unroll
        for (int d = 0; d < DD; ++d) {
            dot += ci[d] * g[d];
            if (ci[d] > mx) { mx = ci[d]; lab = d; }   // strict > keeps first index
        }
        atomicAdd(&hist_in[lab], 1);
        cls_dots += dot;
    }
    {   // term 2: class_input[idx2[t]] . class_pred[t]; label of class_pred row t
        float cp[DD];
        #pragma unroll
        for (int d = 0; d < DD; ++d) cp[d] = cp_base[t * DD + d];
        const float* g = ci_base + (size_t)bidx2 * DD;
        float dot = 0.f, mx = cp[0]; int lab = 0;
        #pragma unroll
        for (int d = 0; d < DD; ++d) {
            dot += cp[d] * g[d];
            if (cp[d] > mx) { mx = cp[d]; lab = d; }   // argmax(exp(x)) == argmax(x)
        }
        atomicAdd(&hist_pr[lab], 1);
        cls_dots += dot;
    }

    // chamfer partial + W*class_loss partial (W=1, class_loss = -sum(dots))
    float part = best1 + best2 - cls_dots;

    // ---- KL (wave 0, lanes 0..31 carry values) ----
    if (t < 64) {
        float v = 0.f;
        if (t < LL) {
            float m_ = mu[(size_t)b * LL + t];
            float lv = log_var[(size_t)b * LL + t];
            v = 1.f + lv - m_ * m_ - expf(lv);
        }
        #pragma unroll
        for (int off = 32; off > 0; off >>= 1) v += __shfl_down(v, off, 64);
        if (t == 0) s_kl = -0.5f * v;
    }

    // ---- block reduce `part` ----
    #pragma unroll
    for (int off = 32; off > 0; off >>= 1) part += __shfl_down(part, off, 64);
    if ((t & 63) == 0) red[t >> 6] = part;
    __syncthreads();

    if (t == 0) {
        float chamcls = 0.f;
        #pragma unroll
        for (int w = 0; w < 8; ++w) chamcls += red[w];

        float cnum = 0.f;
        #pragma unroll
        for (int c = 0; c < DD; ++c) {
            float diff = fabsf((float)(hist_pr[c] - hist_in[c]));
            float wgt = (c == 0) ? 2.0f : ((c == DD - 1) ? 100.0f : 1.0f);
            cnum += wgt * diff;
        }
        // total = (1-BETA)*(chamfer + W*class + C*classnum) + BETA*kl
        out[b] = 0.99f * (chamcls + 0.001f * cnum) + 0.01f * s_kl;
    }
}

extern "C" void kernel_launch(void* const* d_in, const int* in_sizes, int n_in,
                              void* d_out, int out_size, void* d_ws, size_t ws_size,
                              hipStream_t stream) {
    const float* kine_input  = (const float*)d_in[0];
    const float* class_input = (const float*)d_in[1];
    const float* kine_pred   = (const float*)d_in[2];
    const float* class_pred  = (const float*)d_in[3];
    const float* mu          = (const float*)d_in[4];
    const float* log_var     = (const float*)d_in[5];
    float* out = (float*)d_out;

    loss_kernel<<<256, 512, 0, stream>>>(kine_input, class_input, kine_pred,
                                         class_pred, mu, log_var, out);
}

// Round 2
// 36.855 us; speedup vs baseline: 1.4508x; 1.4508x over previous
//
#include <hip/hip_runtime.h>

#define NN 512   // points per event (N == M)
#define DD 9     // num classes
#define LL 32    // latent dim

// grid = 512 blocks: block (b, h) handles batch b = blockIdx>>1, half h = blockIdx&1.
// Threads 0-255: pass1 (input rows h*256..h*256+255), threads 256-511: pass2 (pred cols).
// Each thread owns 4 rows (register tile) x 128 m-values (stride-4 segment).
__global__ __launch_bounds__(512, 4)
void loss_kernel(const float* __restrict__ kine_input,
                 const float* __restrict__ class_input,
                 const float* __restrict__ kine_pred,
                 const float* __restrict__ class_pred,
                 const float* __restrict__ mu,
                 const float* __restrict__ log_var,
                 float* __restrict__ out)
{
    const int b = (int)blockIdx.x >> 1;
    const int h = (int)blockIdx.x & 1;
    const int t = (int)threadIdx.x;

    __shared__ float4 sp4[NN];              // raw kine_pred points
    __shared__ float  sp2[NN];              // |pred|^2
    __shared__ float4 si4[NN];              // raw kine_input points
    __shared__ float  si2[NN];              // |input|^2
    __shared__ float  comb_d[2][4][257];    // per-segment partial min dist (padded)
    __shared__ int    comb_i[2][4][257];    // per-segment partial argmin
    __shared__ float  red[8];
    __shared__ int    hist_in[DD], hist_pr[DD];

    // ---- stage both point sets (full), plus squared norms ----
    {
        float4 pv = *reinterpret_cast<const float4*>(kine_pred + ((size_t)b*NN + t)*4);
        sp4[t] = pv;
        sp2[t] = pv.x*pv.x + pv.y*pv.y + pv.z*pv.z + pv.w*pv.w;
        float4 iv = *reinterpret_cast<const float4*>(kine_input + ((size_t)b*NN + t)*4);
        si4[t] = iv;
        si2[t] = iv.x*iv.x + iv.y*iv.y + iv.z*iv.z + iv.w*iv.w;
    }
    if (t < DD) { hist_in[t] = 0; hist_pr[t] = 0; }
    __syncthreads();

    // ---- histograms + KL: block h==0 only (labels independent of argmins) ----
    float kl = 0.f;
    if (h == 0) {
        const float* ci = class_input + ((size_t)b*NN + t)*DD;
        float mx = ci[0]; int lab = 0;
        #pragma unroll
        for (int d2 = 1; d2 < DD; ++d2) { float v = ci[d2]; if (v > mx) { mx = v; lab = d2; } }
        atomicAdd(&hist_in[lab], 1);
        const float* cp = class_pred + ((size_t)b*NN + t)*DD;
        mx = cp[0]; lab = 0;
        #pragma unroll
        for (int d2 = 1; d2 < DD; ++d2) { float v = cp[d2]; if (v > mx) { mx = v; lab = d2; } }   // argmax(exp(x)) == argmax(x)
        atomicAdd(&hist_pr[lab], 1);

        if (t < LL) {
            float m_ = mu[(size_t)b*LL + t];
            float lv = log_var[(size_t)b*LL + t];
            kl = 1.f + lv - m_*m_ - expf(lv);
        }
    }
    if (t < 64) {   // reduce KL over wave 0 (lanes >=32 and h==1 hold 0)
        #pragma unroll
        for (int off = 32; off > 0; off >>= 1) kl += __shfl_down(kl, off, 64);
    }

    // ---- distance passes (register-tiled R=4, m-segmented x4) ----
    const int p    = t >> 8;        // 0: input rows vs preds; 1: pred cols vs inputs
    const int tl   = t & 255;
    const int rg   = tl >> 2;       // row group 0..63
    const int seg  = tl & 3;        // m-segment
    const int lrow0 = rg * 4;       // local row base 0..252
    const int grow0 = h*256 + lrow0;

    const float4* X4 = p ? sp4 : si4;
    const float*  X2 = p ? sp2 : si2;
    const float4* Y4 = p ? si4 : sp4;
    const float*  Y2 = p ? si2 : sp2;

    float4 a[4]; float x2q[4]; float best[4]; int bidx[4];
    #pragma unroll
    for (int q = 0; q < 4; ++q) {
        float4 xv = X4[grow0 + q];
        a[q] = make_float4(-2.f*xv.x, -2.f*xv.y, -2.f*xv.z, -2.f*xv.w);
        x2q[q] = X2[grow0 + q];
        best[q] = 1e30f; bidx[q] = 0;
    }

    #pragma unroll 2
    for (int j = 0; j < 128; ++j) {
        const int m = seg + 4*j;
        float4 yv = Y4[m];      // 4 distinct addrs/wave, 16-lane broadcast: conflict-free
        float  y2 = Y2[m];
        #pragma unroll
        for (int q = 0; q < 4; ++q) {
            float s = x2q[q] + y2;
            float d = fmaf(a[q].x, yv.x, fmaf(a[q].y, yv.y,
                      fmaf(a[q].z, yv.z, fmaf(a[q].w, yv.w, s))));
            d = fmaxf(d, 0.f);                                    // matches jnp.maximum(...,0)
            if (d < best[q]) { best[q] = d; bidx[q] = m; }        // strict <: first index
        }
    }

    #pragma unroll
    for (int q = 0; q < 4; ++q) {
        comb_d[p][seg][lrow0 + q] = best[q];
        comb_i[p][seg][lrow0 + q] = bidx[q];
    }
    __syncthreads();

    // ---- per-row finalize: thread t owns (pass p, local row tl) ----
    float part;
    {
        const int lr = tl;
        float bd = comb_d[p][0][lr]; int bi = comb_i[p][0][lr];
        #pragma unroll
        for (int s2 = 1; s2 < 4; ++s2) {
            float d = comb_d[p][s2][lr]; int i2 = comb_i[p][s2][lr];
            if (d < bd || (d == bd && i2 < bi)) { bd = d; bi = i2; }  // global first-index argmin
        }
        const int grow = h*256 + lr;
        const float* own = (p ? class_pred : class_input) + ((size_t)b*NN + grow)*DD;
        const float* oth = (p ? class_input : class_pred) + ((size_t)b*NN + bi)*DD;
        float dot = 0.f;
        #pragma unroll
        for (int d2 = 0; d2 < DD; ++d2) dot += own[d2]*oth[d2];
        part = bd - dot;   // chamfer term + (-1)*class dot, W=1
    }

    // ---- block reduce ----
    #pragma unroll
    for (int off = 32; off > 0; off >>= 1) part += __shfl_down(part, off, 64);
    if ((t & 63) == 0) red[t >> 6] = part;
    __syncthreads();

    if (t == 0) {
        float sum = 0.f;
        #pragma unroll
        for (int w = 0; w < 8; ++w) sum += red[w];
        float val = 0.99f * sum;
        if (h == 0) {
            float cnum = 0.f;
            #pragma unroll
            for (int c = 0; c < DD; ++c) {
                float diff = fabsf((float)(hist_pr[c] - hist_in[c]));
                float wgt = (c == 0) ? 2.0f : ((c == DD-1) ? 100.0f : 1.0f);
                cnum += wgt * diff;
            }
            val += 0.99f * 0.001f * cnum + 0.01f * (-0.5f * kl);
        }
        atomicAdd(out + b, val);
    }
}

extern "C" void kernel_launch(void* const* d_in, const int* in_sizes, int n_in,
                              void* d_out, int out_size, void* d_ws, size_t ws_size,
                              hipStream_t stream) {
    const float* kine_input  = (const float*)d_in[0];
    const float* class_input = (const float*)d_in[1];
    const float* kine_pred   = (const float*)d_in[2];
    const float* class_pred  = (const float*)d_in[3];
    const float* mu          = (const float*)d_in[4];
    const float* log_var     = (const float*)d_in[5];
    float* out = (float*)d_out;

    hipMemsetAsync(d_out, 0, (size_t)out_size * sizeof(float), stream);
    loss_kernel<<<512, 512, 0, stream>>>(kine_input, class_input, kine_pred,
                                         class_pred, mu, log_var, out);
}